// Round 18
// baseline (282.005 us; speedup 1.0000x reference)
//
#include <hip/hip_runtime.h>
#include <hip/hip_fp16.h>

#define N_NODES 50000
#define N_EDGES 600000
#define N_GRAPHS 64
#define HID 128
#define OUT_C 32

#define N_SCAN_BLOCKS ((N_NODES + 255) / 256)   // 196
#define SCAN_FLAG 0x40000000

typedef __attribute__((ext_vector_type(8))) _Float16 half8;
typedef __attribute__((ext_vector_type(4))) float f32x4;

// ================= prep: zero {pooled,degi,bsum} + fp16 casts + graph boundaries ==========
#define ZERO_INTS (N_GRAPHS * 128 + N_NODES + N_SCAN_BLOCKS)   // pooled + degi + bsum

__global__ __launch_bounds__(256) void prep_kernel(
    const float* __restrict__ x, const int* __restrict__ batch,
    const float* __restrict__ W1l, const float* __restrict__ W1r,
    const float* __restrict__ W2l, const float* __restrict__ W2r,
    __half* __restrict__ xh, __half* __restrict__ Wt1, __half* __restrict__ Wt2,
    int* __restrict__ zero_base, int* __restrict__ gstart) {
    const int b = blockIdx.x;
    const int t = threadIdx.x;
    const int gtid = b * 256 + t;
    const int gsz = gridDim.x * 256;
    for (int i = gtid; i < ZERO_INTS; i += gsz) zero_base[i] = 0;

    // graph boundaries from sorted batch
    for (int i = gtid; i <= N_NODES; i += gsz) {
        if (i == 0) {
            int b1 = batch[0];
            for (int g = 0; g <= b1; ++g) gstart[g] = 0;
        } else if (i == N_NODES) {
            int b0 = batch[N_NODES - 1];
            for (int g = b0 + 1; g <= N_GRAPHS; ++g) gstart[g] = N_NODES;
        } else {
            int b0 = batch[i - 1], b1 = batch[i];
            for (int g = b0 + 1; g <= b1; ++g) gstart[g] = i;
        }
    }

    if (b < 16) {
        for (int i = gtid; i < 65536; i += 4096) {
            int which = i >> 15;
            int j = i & 32767;
            int n = j >> 8, k = j & 255;
            const float* Wl = which ? W2l : W1l;
            const float* Wr = which ? W2r : W1r;
            float a = (k < 128) ? Wl[n * 128 + k] : Wr[n * 128 + (k - 128)];
            (which ? Wt2 : Wt1)[j] = __float2half(a);
        }
    } else {
        int i = ((b - 16) * 256 + t) * 4;
        if (i < N_NODES * 128) {
            float4 v = *(const float4*)(x + i);
            __half2 a = __floats2half2_rn(v.x, v.y);
            __half2 c = __floats2half2_rn(v.z, v.w);
            uint2 st;
            st.x = *(const unsigned int*)&a;
            st.y = *(const unsigned int*)&c;
            *(uint2*)(xh + i) = st;
        }
    }
}

// ================= CSR: degrees =================
__global__ void deg_kernel(const int* __restrict__ dst, int* __restrict__ deg, int E) {
    int e = blockIdx.x * 256 + threadIdx.x;
    if (e < E) atomicAdd(&deg[dst[e]], 1);
}

// ================= CSR: single-dispatch scan (decoupled lookback); inits cursor ==========
__global__ __launch_bounds__(256) void scan_fused(
    const int* __restrict__ deg, int* __restrict__ bsum,
    int* __restrict__ rowptr, int* __restrict__ cursor, float* __restrict__ invdeg) {
    __shared__ int s[256];
    const int b = blockIdx.x;
    const int t = threadIdx.x;
    const int idx = b * 256 + t;
    const int v = (idx < N_NODES) ? deg[idx] : 0;
    s[t] = v;
    __syncthreads();
    for (int off = 1; off < 256; off <<= 1) {
        int u = (t >= off) ? s[t - off] : 0;
        __syncthreads();
        s[t] += u;
        __syncthreads();
    }
    const int incl = s[t];
    if (t == 255) atomicExch(&bsum[b], incl | SCAN_FLAG);

    int pv = 0;
    if (t < b) {
        int w;
        do { w = atomicAdd(&bsum[t], 0); } while (!(w & SCAN_FLAG));
        pv = w & ~SCAN_FLAG;
    }
    __syncthreads();
    s[t] = pv;
    __syncthreads();
    for (int off = 128; off > 0; off >>= 1) {
        if (t < off) s[t] += s[t + off];
        __syncthreads();
    }
    const int boffs = s[0];

    if (idx < N_NODES) {
        int rp = boffs + incl - v;
        rowptr[idx] = rp;
        cursor[idx] = rp;
        invdeg[idx] = 1.0f / fmaxf((float)v, 1.0f);
    }
    if (b == N_SCAN_BLOCKS - 1 && t == 255) rowptr[N_NODES] = boffs + incl;
}

// ================= CSR: fill (single atomic, absolute position) =================
__global__ void fill_kernel(const int* __restrict__ src, const int* __restrict__ dst,
                            int* __restrict__ cursor, int* __restrict__ eidx, int E) {
    int e = blockIdx.x * 256 + threadIdx.x;
    if (e < E) {
        int pos = atomicAdd(&cursor[dst[e]], 1);
        eidx[pos] = src[e];
    }
}

// ================= fused SAGE layer, aggregate-shaped grid (3125 blocks x 16 rows) ========
// Phase 1 (proven agg shape): 4 waves x 4 nodes, 16 lanes x 16 B gather -> mean into LDS.
// Phase 2: each wave computes the block's 16 rows x 32 cols (t = 2*wave, 2*wave+1) with
// 16 MFMAs; A low-half from LDS, A high-half from feat16, B per-lane from L2-hot Wt
// (16 independent loads; 12+ blocks/CU hide the L2 latency - the R14 failure had ~1).
// Layer 2 (pooled != nullptr): pooling fused into epilogue via pool_lds (<=2 graphs/block).
#define AGG8(vv, aa, ab) { aa.x += (float)vv[0]; aa.y += (float)vv[1]; \
                           aa.z += (float)vv[2]; aa.w += (float)vv[3]; \
                           ab.x += (float)vv[4]; ab.y += (float)vv[5]; \
                           ab.z += (float)vv[6]; ab.w += (float)vv[7]; }

__global__ __launch_bounds__(256, 4) void sage_layer_fused(
    const __half* __restrict__ feat16, const int* __restrict__ rowptr,
    const int* __restrict__ eidx, const float* __restrict__ invdeg,
    const __half* __restrict__ Wt, const float* __restrict__ bias,
    const int* __restrict__ batch, __half* __restrict__ out16,
    float* __restrict__ pooled) {
    __shared__ __align__(16) __half As[16][136];
    __shared__ float pool_lds[4][128];

    const int tid  = threadIdx.x;
    const int wave = tid >> 6;
    const int lane = tid & 63;
    const int nh   = lane >> 4;          // node-in-wave (gather) / k-chunk quad (gemm)
    const int sub  = lane & 15;          // col-chunk (gather) / row|col l15 (gemm)
    const int row0 = blockIdx.x * 16;    // 50000 = 3125*16 exactly: no OOB rows
    const int node = row0 + wave * 4 + nh;
    const size_t coff = (size_t)sub * 8;

    if (pooled) {
        for (int i = tid; i < 4 * 128; i += 256) pool_lds[i >> 7][i & 127] = 0.f;
    }

    // ---- phase 1: gather mean for this block's 16 rows (proven 4-node/wave shape)
    {
        const int beg = rowptr[node];
        const int end = rowptr[node + 1];
        float4 a0 = {0.f,0.f,0.f,0.f}, b0 = {0.f,0.f,0.f,0.f};
        float4 a1 = {0.f,0.f,0.f,0.f}, b1 = {0.f,0.f,0.f,0.f};
        float4 a2 = {0.f,0.f,0.f,0.f}, b2 = {0.f,0.f,0.f,0.f};
        float4 a3 = {0.f,0.f,0.f,0.f}, b3 = {0.f,0.f,0.f,0.f};
        int i = beg;
        for (; i + 8 <= end; i += 8) {
            int s0 = eidx[i+0], s1 = eidx[i+1], s2 = eidx[i+2], s3 = eidx[i+3];
            int s4 = eidx[i+4], s5 = eidx[i+5], s6 = eidx[i+6], s7 = eidx[i+7];
            half8 v0 = *(const half8*)(feat16 + (size_t)s0 * 128 + coff);
            half8 v1 = *(const half8*)(feat16 + (size_t)s1 * 128 + coff);
            half8 v2 = *(const half8*)(feat16 + (size_t)s2 * 128 + coff);
            half8 v3 = *(const half8*)(feat16 + (size_t)s3 * 128 + coff);
            half8 v4 = *(const half8*)(feat16 + (size_t)s4 * 128 + coff);
            half8 v5 = *(const half8*)(feat16 + (size_t)s5 * 128 + coff);
            half8 v6 = *(const half8*)(feat16 + (size_t)s6 * 128 + coff);
            half8 v7 = *(const half8*)(feat16 + (size_t)s7 * 128 + coff);
            AGG8(v0, a0, b0); AGG8(v1, a1, b1); AGG8(v2, a2, b2); AGG8(v3, a3, b3);
            AGG8(v4, a0, b0); AGG8(v5, a1, b1); AGG8(v6, a2, b2); AGG8(v7, a3, b3);
        }
        if (i + 4 <= end) {
            int s0 = eidx[i+0], s1 = eidx[i+1], s2 = eidx[i+2], s3 = eidx[i+3];
            half8 v0 = *(const half8*)(feat16 + (size_t)s0 * 128 + coff);
            half8 v1 = *(const half8*)(feat16 + (size_t)s1 * 128 + coff);
            half8 v2 = *(const half8*)(feat16 + (size_t)s2 * 128 + coff);
            half8 v3 = *(const half8*)(feat16 + (size_t)s3 * 128 + coff);
            AGG8(v0, a0, b0); AGG8(v1, a1, b1); AGG8(v2, a2, b2); AGG8(v3, a3, b3);
            i += 4;
        }
        if (i + 2 <= end) {
            int s0 = eidx[i+0], s1 = eidx[i+1];
            half8 v0 = *(const half8*)(feat16 + (size_t)s0 * 128 + coff);
            half8 v1 = *(const half8*)(feat16 + (size_t)s1 * 128 + coff);
            AGG8(v0, a0, b0); AGG8(v1, a1, b1);
            i += 2;
        }
        if (i < end) {
            int s0 = eidx[i];
            half8 v0 = *(const half8*)(feat16 + (size_t)s0 * 128 + coff);
            AGG8(v0, a0, b0);
        }

        const float sc = invdeg[node];
        half8 r;
        r[0] = (_Float16)(((a0.x + a1.x) + (a2.x + a3.x)) * sc);
        r[1] = (_Float16)(((a0.y + a1.y) + (a2.y + a3.y)) * sc);
        r[2] = (_Float16)(((a0.z + a1.z) + (a2.z + a3.z)) * sc);
        r[3] = (_Float16)(((a0.w + a1.w) + (a2.w + a3.w)) * sc);
        r[4] = (_Float16)(((b0.x + b1.x) + (b2.x + b3.x)) * sc);
        r[5] = (_Float16)(((b0.y + b1.y) + (b2.y + b3.y)) * sc);
        r[6] = (_Float16)(((b0.z + b1.z) + (b2.z + b3.z)) * sc);
        r[7] = (_Float16)(((b0.w + b1.w) + (b2.w + b3.w)) * sc);
        *(half8*)&As[wave * 4 + nh][sub * 8] = r;
    }

    __syncthreads();

    // ---- phase 2: GEMM for this block's 16 rows; wave handles cols t in {2w, 2w+1}
    const int l15 = sub;        // row (A) / col-in-tile (B,C)
    const int quad = nh;        // k-chunk / row-quad

    // A fragments: kb<4 from LDS mean, kb>=4 from feat16 (k-128)
    half8 af[8];
#pragma unroll
    for (int kb = 0; kb < 4; ++kb)
        af[kb] = *(const half8*)&As[l15][kb * 32 + quad * 8];
#pragma unroll
    for (int kb = 4; kb < 8; ++kb)
        af[kb] = *(const half8*)(feat16 + (size_t)(row0 + l15) * 128 + (kb - 4) * 32 + quad * 8);

    const int gmin = pooled ? batch[row0] : 0;

#pragma unroll
    for (int tt = 0; tt < 2; ++tt) {
        const int tcol = 2 * wave + tt;
        // B fragments for this col-tile: 8 independent loads from L2-hot Wt
        half8 bf[8];
#pragma unroll
        for (int kb = 0; kb < 8; ++kb)
            bf[kb] = *(const half8*)(Wt + (size_t)(tcol * 16 + l15) * 256 + kb * 32 + quad * 8);

        f32x4 acc = (f32x4){0.f, 0.f, 0.f, 0.f};
#pragma unroll
        for (int kb = 0; kb < 8; ++kb)
            acc = __builtin_amdgcn_mfma_f32_16x16x32_f16(af[kb], bf[kb], acc, 0, 0, 0);

        const int col = tcol * 16 + l15;
        const float bv = bias[col];
        if (pooled) {
#pragma unroll
            for (int r = 0; r < 4; ++r) {
                int row = row0 + quad * 4 + r;
                float v = fmaxf(acc[r] + bv, 0.f);
                int gl = batch[row] - gmin;
                if (gl < 4) atomicAdd(&pool_lds[gl][col], v);
                else        atomicAdd(&pooled[(gmin + gl) * 128 + col], v);
            }
        } else {
#pragma unroll
            for (int r = 0; r < 4; ++r) {
                int row = row0 + quad * 4 + r;
                float v = fmaxf(acc[r] + bv, 0.f);
                out16[(size_t)row * 128 + col] = __float2half(v);
            }
        }
    }

    if (pooled) {
        __syncthreads();
        for (int i = tid; i < 4 * 128; i += 256) {
            int gl = i >> 7, c = i & 127;
            float v = pool_lds[gl][c];
            if (v != 0.f) atomicAdd(&pooled[(gmin + gl) * 128 + c], v);
        }
    }
}

// ================= final linear =================
__global__ void final_kernel(const float* __restrict__ pooled,
                             const int* __restrict__ gstart,
                             const float* __restrict__ Wlin, const float* __restrict__ blin,
                             float* __restrict__ out) {
    int g = blockIdx.x;
    int j = threadIdx.x;               // 0..31
    float inv = 1.0f / fmaxf((float)(gstart[g + 1] - gstart[g]), 1.0f);
    float sum = blin[j];
    const float* w = Wlin + j * 128;
    const float* p = pooled + (size_t)g * 128;
    for (int c = 0; c < 128; ++c) sum += p[c] * inv * w[c];
    out[g * 32 + j] = sum;
}

extern "C" void kernel_launch(void* const* d_in, const int* in_sizes, int n_in,
                              void* d_out, int out_size, void* d_ws, size_t ws_size,
                              hipStream_t stream) {
    const float* x    = (const float*)d_in[0];
    const int*   src  = (const int*)d_in[1];
    const int*   dst  = ((const int*)d_in[1]) + N_EDGES;
    const int*   batch= (const int*)d_in[2];
    const float* W1l  = (const float*)d_in[3];
    const float* b1   = (const float*)d_in[4];
    const float* W1r  = (const float*)d_in[5];
    const float* W2l  = (const float*)d_in[6];
    const float* b2   = (const float*)d_in[7];
    const float* W2r  = (const float*)d_in[8];
    const float* Wlin = (const float*)d_in[9];
    const float* blin = (const float*)d_in[10];
    float* out = (float*)d_out;

    __half* xh     = (__half*)d_ws;                 // 6,400,000 h
    __half* h1_16  = xh + 6400000;                  // 6,400,000 h
    __half* Wt1    = h1_16 + 6400000;               // 32,768 h
    __half* Wt2    = Wt1 + 32768;                   // 32,768 h
    float* invdeg  = (float*)(Wt2 + 32768);         // 50,000 f
    int*   gstart  = (int*)(invdeg + N_NODES);      // 65 i
    // contiguous zero region: pooled, degi, bsum
    float* pooled  = (float*)(gstart + 65);         // 8,192 f
    int*   degi    = (int*)(pooled + N_GRAPHS * 128); // 50,000 i
    int*   bsum    = degi + N_NODES;                // 196 i
    int*   cursor  = bsum + N_SCAN_BLOCKS;          // 50,000 i (init'd by scan)
    int*   rowptr  = cursor + N_NODES;              // 50,001 i
    int*   eidx    = rowptr + N_NODES + 1;          // 600,000 i

    // 1) prep: zero {pooled,degi,bsum} + casts + graph boundaries
    prep_kernel<<<16 + (N_NODES * 128 / 4 + 255) / 256, 256, 0, stream>>>(
        x, batch, W1l, W1r, W2l, W2r, xh, Wt1, Wt2, (int*)pooled, gstart);

    // 2-4) CSR: degrees -> fused lookback scan (inits cursor) -> fill
    deg_kernel<<<(N_EDGES + 255) / 256, 256, 0, stream>>>(dst, degi, N_EDGES);
    scan_fused<<<N_SCAN_BLOCKS, 256, 0, stream>>>(degi, bsum, rowptr, cursor, invdeg);
    fill_kernel<<<(N_EDGES + 255) / 256, 256, 0, stream>>>(src, dst, cursor, eidx, N_EDGES);

    const int layer_grid = N_NODES / 16;   // 3125 (exact)

    // 5) layer 1 fused (gather + GEMM -> h1 fp16)
    sage_layer_fused<<<layer_grid, 256, 0, stream>>>(
        xh, rowptr, eidx, invdeg, Wt1, b1, batch, h1_16, (float*)nullptr);

    // 6) layer 2 fused (gather + GEMM + pooling; h2 never materialized)
    sage_layer_fused<<<layer_grid, 256, 0, stream>>>(
        h1_16, rowptr, eidx, invdeg, Wt2, b2, batch, (__half*)nullptr, pooled);

    // 7) final linear
    final_kernel<<<N_GRAPHS, 32, 0, stream>>>(pooled, gstart, Wlin, blin, out);
}